// Round 6
// baseline (416.293 us; speedup 1.0000x reference)
//
#include <hip/hip_runtime.h>
#include <stdint.h>

#define N_NODES 50000
#define N_PAD   50048      // 391 * 128
#define GQ      8
#define EE      400000
#define DIM     512
#define NE_TOT  450000     // E + N self loops
#define NBLK_SCAN 196

typedef __attribute__((ext_vector_type(8))) __bf16 bf16x8;
typedef __attribute__((ext_vector_type(4))) float f32x4;

// ---------------- helpers ----------------
__device__ __forceinline__ float bf2f(unsigned short u){ return __uint_as_float(((unsigned)u) << 16); }
__device__ __forceinline__ unsigned short f2bf(float f){
  unsigned u = __float_as_uint(f);
  return (unsigned short)((u + 0x7fffu + ((u >> 16) & 1u)) >> 16);
}
__device__ __forceinline__ unsigned pk2(float lo, float hi){
  return (unsigned)f2bf(lo) | ((unsigned)f2bf(hi) << 16);
}
__device__ __forceinline__ float dot4(float4 a, float4 b){ return a.x*b.x + a.y*b.y + a.z*b.z + a.w*b.w; }
__device__ __forceinline__ float wredSum(float v){
#pragma unroll
  for (int o = 32; o > 0; o >>= 1) v += __shfl_xor(v, o, 64);
  return v;
}
__device__ __forceinline__ int wredSumI(int v){
#pragma unroll
  for (int o = 32; o > 0; o >>= 1) v += __shfl_xor(v, o, 64);
  return v;
}
__device__ __forceinline__ float wredMax(float v){
#pragma unroll
  for (int o = 32; o > 0; o >>= 1) v = fmaxf(v, __shfl_xor(v, o, 64));
  return v;
}
__device__ __forceinline__ void gload_lds16(const void* g, void* l){
  __builtin_amdgcn_global_load_lds((__attribute__((address_space(1))) void*)g,
                                   (__attribute__((address_space(3))) void*)l, 16, 0, 0);
}
// fp8 e4m3 HW codec (self-consistent encode+decode on gfx950)
__device__ __forceinline__ unsigned char f2fp8(float x){
  return (unsigned char)__builtin_amdgcn_cvt_pk_fp8_f32(x, x, 0, false);
}
__device__ __forceinline__ unsigned pk4f8(float a, float b, float c, float d){
  unsigned w = (unsigned)__builtin_amdgcn_cvt_pk_fp8_f32(a, b, 0, false);
  return (unsigned)__builtin_amdgcn_cvt_pk_fp8_f32(c, d, (int)w, true);
}
// 16 fp8 channels (uint4) weighted-accumulate into ac[16]
__device__ __forceinline__ void consume16(float* ac, uint4 u, float al){
  auto p0 = __builtin_amdgcn_cvt_pk_f32_fp8(u.x, false);
  auto p1 = __builtin_amdgcn_cvt_pk_f32_fp8(u.x, true);
  auto p2 = __builtin_amdgcn_cvt_pk_f32_fp8(u.y, false);
  auto p3 = __builtin_amdgcn_cvt_pk_f32_fp8(u.y, true);
  auto p4 = __builtin_amdgcn_cvt_pk_f32_fp8(u.z, false);
  auto p5 = __builtin_amdgcn_cvt_pk_f32_fp8(u.z, true);
  auto p6 = __builtin_amdgcn_cvt_pk_f32_fp8(u.w, false);
  auto p7 = __builtin_amdgcn_cvt_pk_f32_fp8(u.w, true);
  ac[0]  += al * p0[0]; ac[1]  += al * p0[1];
  ac[2]  += al * p1[0]; ac[3]  += al * p1[1];
  ac[4]  += al * p2[0]; ac[5]  += al * p2[1];
  ac[6]  += al * p3[0]; ac[7]  += al * p3[1];
  ac[8]  += al * p4[0]; ac[9]  += al * p4[1];
  ac[10] += al * p5[0]; ac[11] += al * p5[1];
  ac[12] += al * p6[0]; ac[13] += al * p6[1];
  ac[14] += al * p7[0]; ac[15] += al * p7[1];
}

// ---------------- workspace layout ----------------
static constexpr size_t AL(size_t x){ return (x + 255) & ~(size_t)255; }
static constexpr size_t OFF_XBF   = 0;
static constexpr size_t OFF_HF8   = OFF_XBF   + AL((size_t)N_PAD * DIM * 2);
static constexpr size_t OFF_HCV8  = OFF_HF8   + AL((size_t)N_PAD * DIM);
static constexpr size_t OFF_WTBF  = OFF_HCV8  + AL((size_t)N_NODES * DIM);
static constexpr size_t OFF_WNT   = OFF_WTBF  + AL((size_t)DIM * DIM * 2);
static constexpr size_t OFF_W1T   = OFF_WNT   + AL((size_t)DIM * DIM * 4);
static constexpr size_t OFF_WSS   = OFF_W1T   + AL((size_t)DIM * DIM * 4);
static constexpr size_t OFF_WSD   = OFF_WSS   + AL((size_t)DIM * 4);
static constexpr size_t OFF_AS    = OFF_WSD   + AL((size_t)DIM * 4);
static constexpr size_t OFF_AD    = OFF_AS    + AL((size_t)N_NODES * 4);
static constexpr size_t OFF_GATE  = OFF_AD    + AL((size_t)N_NODES * 4);
static constexpr size_t OFF_CNT   = OFF_GATE  + AL((size_t)N_NODES * 4);
static constexpr size_t OFF_FILL  = OFF_CNT   + AL((size_t)N_NODES * 4);
static constexpr size_t OFF_RS    = OFF_FILL  + AL((size_t)N_NODES * 4);
static constexpr size_t OFF_CSR2  = OFF_RS    + AL((size_t)(N_NODES + 1) * 4);
static constexpr size_t OFF_BSUM  = OFF_CSR2  + AL((size_t)NE_TOT * 8);
static constexpr size_t OFF_GSUM  = OFF_BSUM  + AL((size_t)NBLK_SCAN * 4);
static constexpr size_t OFF_PP    = OFF_GSUM  + AL((size_t)GQ * 4);
static constexpr size_t OFF_POOL  = OFF_PP    + AL((size_t)GQ * DIM * 4);
static constexpr size_t OFF_Z1    = OFF_POOL  + AL((size_t)GQ * DIM * 4);

// ---------------- kernels ----------------

// fused: init (cnt/fill/gsum/pp) + ws_s/ws_d = W@att_{src,dst} + 3x 512x512 transpose
__global__ void k_setup(const float* __restrict__ W, const float* __restrict__ atS,
                        const float* __restrict__ atD, const float* __restrict__ Wn,
                        const float* __restrict__ W1,
                        float* ws_s, float* ws_d,
                        unsigned short* __restrict__ WtBf, float* __restrict__ WnT,
                        float* __restrict__ W1T,
                        int* cnt, int* fill, float* gsum, float* pp){
  __shared__ float tile[64][65];
  int bx = blockIdx.x;
  if (bx < NBLK_SCAN){
    int i = bx * 256 + threadIdx.x;
    if (i < N_NODES){ cnt[i] = 1; fill[i] = 0; }    // 1 = self-loop slot
    if (i < GQ) gsum[i] = 0.f;
    if (i < GQ * DIM) pp[i] = 0.f;
    if (bx < 128){
      int wid = threadIdx.x >> 6, lane = threadIdx.x & 63;
      int k = bx * 4 + wid;                         // 0..511
      const float4* row = (const float4*)(W + (size_t)k * DIM);
      float4 r0 = row[lane * 2], r1 = row[lane * 2 + 1];
      const float4* s4 = (const float4*)atS;
      const float4* d4 = (const float4*)atD;
      float vs = dot4(r0, s4[lane * 2]) + dot4(r1, s4[lane * 2 + 1]);
      float vd = dot4(r0, d4[lane * 2]) + dot4(r1, d4[lane * 2 + 1]);
      vs = wredSum(vs); vd = wredSum(vd);
      if (lane == 0){ ws_s[k] = vs; ws_d[k] = vd; }
    }
  } else {
    int tb = bx - NBLK_SCAN;
    int y = tb >> 6, bq = tb & 63;
    const float* src = (y == 0) ? W : (y == 1) ? Wn : W1;
    int bi = bq & 7, bj = bq >> 3;
    int r0 = bi * 64, c0 = bj * 64;
#pragma unroll
    for (int ii = 0; ii < 16; ++ii){
      int idx = ii * 256 + threadIdx.x;
      int r = idx >> 6, c = idx & 63;
      tile[r][c] = src[(size_t)(r0 + r) * DIM + c0 + c];
    }
    __syncthreads();
#pragma unroll
    for (int ii = 0; ii < 16; ++ii){
      int idx = ii * 256 + threadIdx.x;
      int cc = idx >> 6, rr = idx & 63;
      float v = tile[rr][cc];
      size_t o = (size_t)(c0 + cc) * DIM + r0 + rr;
      if (y == 0) WtBf[o] = f2bf(v);
      else if (y == 1) WnT[o] = v;
      else W1T[o] = v;
    }
  }
}

// cast x -> bf16 (zero pad rows), a_s/a_d per row, + fused edge histogram
__global__ __launch_bounds__(256) void k_cast(const float* __restrict__ x,
                                              const float* __restrict__ ws_s,
                                              const float* __restrict__ ws_d,
                                              const int* __restrict__ ei, int* cnt,
                                              unsigned short* __restrict__ x_bf,
                                              float* __restrict__ a_s, float* __restrict__ a_d){
  int gt = blockIdx.x * 256 + threadIdx.x;
  if (gt < EE) atomicAdd(&cnt[ei[EE + gt]], 1);
  int wid = threadIdx.x >> 6, lane = threadIdx.x & 63;
  size_t i = (size_t)blockIdx.x * 4 + wid;
  if (i >= N_PAD) return;
  unsigned short* orow = x_bf + i * DIM;
  if (i >= N_NODES){
    ((uint4*)orow)[lane] = make_uint4(0, 0, 0, 0);
    return;
  }
  const float4* xr = (const float4*)(x + i * DIM);
  float4 v0 = xr[lane * 2], v1 = xr[lane * 2 + 1];
  ((uint4*)orow)[lane] = make_uint4(pk2(v0.x, v0.y), pk2(v0.z, v0.w), pk2(v1.x, v1.y), pk2(v1.z, v1.w));
  const float4* s4 = (const float4*)ws_s;
  const float4* d4 = (const float4*)ws_d;
  float vs = dot4(v0, s4[lane * 2]) + dot4(v1, s4[lane * 2 + 1]);
  float vd = dot4(v0, d4[lane * 2]) + dot4(v1, d4[lane * 2 + 1]);
  vs = wredSum(vs); vd = wredSum(vd);
  if (lane == 0){ a_s[i] = vs; a_d[i] = vd; }
}

// h = x_bf @ W (Bt = W^T, bf16). 128x256 strip tile, 16x16x32 MFMA, XOR bank swizzle.
// Epilogue stores h as fp8 e4m3 (halves k_edge's gather bytes; error budget ok).
__global__ __launch_bounds__(256, 2) void k_gemm(const unsigned short* __restrict__ A,
                                                 const unsigned short* __restrict__ Bt,
                                                 unsigned char* __restrict__ H8){
  __shared__ unsigned short As[128 * 32];   // 8 KB
  __shared__ unsigned short Bs[256 * 32];   // 16 KB
  const int tid = threadIdx.x;
  const int wid = tid >> 6, lane = tid & 63, quad = lane >> 4, l16 = lane & 15;
  const int m0 = blockIdx.x * 128, n0 = blockIdx.y * 256;
  const int wm = (wid & 1) * 64, wn = (wid >> 1) * 128;
  const int qa = quad ^ ((l16 >> 1) & 3);           // swizzled chunk for reads
  f32x4 acc[4][8] = {};
  for (int kt = 0; kt < 16; ++kt){
    const int k0 = kt * 32;
    __syncthreads();
#pragma unroll
    for (int r = 0; r < 2; ++r){                    // A: 512 16B-chunks
      int p = r * 256 + tid;
      int mm = p >> 2;
      int qg = (p & 3) ^ ((mm >> 1) & 3);
      gload_lds16(A + (size_t)(m0 + mm) * DIM + k0 + qg * 8,
                  As + (size_t)(r * 256 + wid * 64) * 8);
    }
#pragma unroll
    for (int r = 0; r < 4; ++r){                    // B: 1024 16B-chunks
      int p = r * 256 + tid;
      int mm = p >> 2;
      int qg = (p & 3) ^ ((mm >> 1) & 3);
      gload_lds16(Bt + (size_t)(n0 + mm) * DIM + k0 + qg * 8,
                  Bs + (size_t)(r * 256 + wid * 64) * 8);
    }
    __syncthreads();
    bf16x8 af[4], bfr[8];
#pragma unroll
    for (int f = 0; f < 4; ++f)
      af[f]  = *(const bf16x8*)(As + (wm + f * 16 + l16) * 32 + qa * 8);
#pragma unroll
    for (int f = 0; f < 8; ++f)
      bfr[f] = *(const bf16x8*)(Bs + (wn + f * 16 + l16) * 32 + qa * 8);
#pragma unroll
    for (int fm = 0; fm < 4; ++fm)
#pragma unroll
      for (int fn = 0; fn < 8; ++fn)
        acc[fm][fn] = __builtin_amdgcn_mfma_f32_16x16x32_bf16(af[fm], bfr[fn], acc[fm][fn], 0, 0, 0);
  }
#pragma unroll
  for (int fm = 0; fm < 4; ++fm){
#pragma unroll
    for (int r = 0; r < 4; ++r){
      size_t gro = (size_t)(m0 + wm + fm * 16 + quad * 4 + r) * DIM + n0 + wn + l16;
#pragma unroll
      for (int fn = 0; fn < 8; ++fn)
        H8[gro + fn * 16] = f2fp8(acc[fm][fn][r]);
    }
  }
}

__global__ void k_scanA(const int* __restrict__ cnt, int* rs, int* bsum){
  __shared__ int sm[256];
  int t = threadIdx.x, i = blockIdx.x * 256 + t;
  int v = (i < N_NODES) ? cnt[i] : 0;
  sm[t] = v; __syncthreads();
#pragma unroll
  for (int off = 1; off < 256; off <<= 1){
    int nv = (t >= off) ? sm[t - off] : 0;
    __syncthreads();
    sm[t] += nv;
    __syncthreads();
  }
  if (i < N_NODES) rs[i] = sm[t] - v;
  if (t == 255) bsum[blockIdx.x] = sm[255];
}

// fused: add block-prefix of bsum, write self-loop csr slot (src=i, a_s[i])
__global__ void k_scanC_fill(int* rs, const int* __restrict__ bsum,
                             const float* __restrict__ a_s, int2* csr2){
  __shared__ int sm4[4];
  int t = threadIdx.x;
  int acc = 0;
  for (int k = t; k < blockIdx.x; k += 256) acc += bsum[k];
  acc = wredSumI(acc);
  if ((t & 63) == 0) sm4[t >> 6] = acc;
  __syncthreads();
  int boff = sm4[0] + sm4[1] + sm4[2] + sm4[3];
  int i = blockIdx.x * 256 + t;
  if (i < N_NODES){
    int v = rs[i] + boff;
    rs[i] = v;
    csr2[v] = make_int2(i, __float_as_int(a_s[i]));  // self-loop at slot 0
  }
  if (i == 0) rs[N_NODES] = NE_TOT;
}

__global__ void k_fill_edges(const int* __restrict__ ei, const int* __restrict__ rs,
                             const float* __restrict__ a_s, int* fill, int2* csr2){
  int e = blockIdx.x * 256 + threadIdx.x;
  if (e < EE){
    int s = ei[e], d = ei[EE + e];
    int p = atomicAdd(&fill[d], 1);
    csr2[rs[d] + 1 + p] = make_int2(s, __float_as_int(a_s[s]));
  }
}

// one wave per dst node, TWO edges per wave iteration (lanes 0-31 edge j, 32-63 edge j+1;
// each lane covers 16 fp8 channels via uint4). Halves loads/shfl/loop-overhead per edge.
// epilogue: cross-half combine, +b_conv, store hconv (fp8), gate = hconv.Wg + bg
// NOTE: no per-node contended global atomics (round-3: 50k atomics on 8 floats = +570us)
__global__ __launch_bounds__(256) void k_edge(const int* __restrict__ rs, const int2* __restrict__ csr2,
                                              const float* __restrict__ a_d,
                                              const unsigned char* __restrict__ h8,
                                              const float* __restrict__ bconv,
                                              const float* __restrict__ Wg, const float* __restrict__ bg,
                                              unsigned char* __restrict__ hconv8, float* __restrict__ gate){
  int wid = threadIdx.x >> 6, lane = threadIdx.x & 63;
  int half = lane >> 5, l32 = lane & 31;
  int i = blockIdx.x * 4 + wid;
  if (i >= N_NODES) return;
  int r0 = rs[i], r1 = rs[i + 1];
  int deg = r1 - r0;
  float adi = a_d[i];
  float ac[16] = {0.f,0.f,0.f,0.f,0.f,0.f,0.f,0.f,0.f,0.f,0.f,0.f,0.f,0.f,0.f,0.f};

  if (deg <= 128){
    int s_l0 = 0, s_l1 = 0;
    float e_a = -__builtin_inff(), e_b = -__builtin_inff();
    if (lane < deg){
      int2 c = csr2[r0 + lane]; s_l0 = c.x;
      float e = __int_as_float(c.y) + adi; e_a = (e > 0.f) ? e : 0.2f * e;
    }
    if (64 + lane < deg){
      int2 c = csr2[r0 + 64 + lane]; s_l1 = c.x;
      float e = __int_as_float(c.y) + adi; e_b = (e > 0.f) ? e : 0.2f * e;
    }
    float mx = wredMax(fmaxf(e_a, e_b));
    float x0 = (lane < deg) ? __expf(e_a - mx) : 0.f;
    float x1 = (64 + lane < deg) ? __expf(e_b - mx) : 0.f;
    float inv = 1.f / (wredSum(x0 + x1) + 1e-16f);

    // pair p covers edges 2p (half 0) and 2p+1 (half 1)
    auto FETCHP = [&](int p, uint4& u, float& al){
      int jj = 2 * p + half;
      bool valid = jj < deg;
      int   sv = (jj < 64) ? s_l0 : s_l1;
      float xv = (jj < 64) ? x0   : x1;
      int   s  = __shfl(sv, jj & 63);
      float a  = __shfl(xv, jj & 63) * inv;
      al = valid ? a : 0.f;
      s  = valid ? s : 0;
      u = *((const uint4*)(h8 + (size_t)s * DIM) + l32);
    };
    int np = (deg + 1) >> 1;
    uint4 u0, u1, u2, u3, u4, u5;
    float f0, f1, f2, f3, f4, f5;
    if (np > 0) FETCHP(0, u0, f0);
    if (np > 1) FETCHP(1, u1, f1);
    if (np > 2) FETCHP(2, u2, f2);
    if (np > 3) FETCHP(3, u3, f3);
    if (np > 4) FETCHP(4, u4, f4);
    if (np > 5) FETCHP(5, u5, f5);
    for (int p = 0; p < np; p += 6){
      consume16(ac, u0, f0); if (p + 6  < np) FETCHP(p + 6,  u0, f0);
      if (p + 1 >= np) break;
      consume16(ac, u1, f1); if (p + 7  < np) FETCHP(p + 7,  u1, f1);
      if (p + 2 >= np) break;
      consume16(ac, u2, f2); if (p + 8  < np) FETCHP(p + 8,  u2, f2);
      if (p + 3 >= np) break;
      consume16(ac, u3, f3); if (p + 9  < np) FETCHP(p + 9,  u3, f3);
      if (p + 4 >= np) break;
      consume16(ac, u4, f4); if (p + 10 < np) FETCHP(p + 10, u4, f4);
      if (p + 5 >= np) break;
      consume16(ac, u5, f5); if (p + 11 < np) FETCHP(p + 11, u5, f5);
    }
  } else {
    // generic fallback (vanishingly rare) — same pair layout, unpipelined
    float mx = -__builtin_inff();
    for (int j = r0 + lane; j < r1; j += 64){
      float e = __int_as_float(csr2[j].y) + adi; e = (e > 0.f) ? e : 0.2f * e;
      mx = fmaxf(mx, e);
    }
    mx = wredMax(mx);
    float ssum = 0.f;
    for (int j = r0 + lane; j < r1; j += 64){
      float e = __int_as_float(csr2[j].y) + adi; e = (e > 0.f) ? e : 0.2f * e;
      ssum += __expf(e - mx);
    }
    float inv = 1.f / (wredSum(ssum) + 1e-16f);
    int np = (deg + 1) >> 1;
    for (int p = 0; p < np; ++p){
      int jj = 2 * p + half;
      float al = 0.f; int s = 0;
      if (jj < deg){
        int2 c = csr2[r0 + jj];
        float e = __int_as_float(c.y) + adi; e = (e > 0.f) ? e : 0.2f * e;
        al = __expf(e - mx) * inv; s = c.x;
      }
      uint4 u = *((const uint4*)(h8 + (size_t)s * DIM) + l32);
      consume16(ac, u, al);
    }
  }

  // combine halves: lanes l and l+32 hold partials for the same 16 channels
#pragma unroll
  for (int k = 0; k < 16; ++k) ac[k] += __shfl_xor(ac[k], 32);

  const float4* b4 = (const float4*)(bconv + l32 * 16);
  float4 bb0 = b4[0], bb1 = b4[1], bb2 = b4[2], bb3 = b4[3];
  ac[0]+=bb0.x; ac[1]+=bb0.y; ac[2]+=bb0.z; ac[3]+=bb0.w;
  ac[4]+=bb1.x; ac[5]+=bb1.y; ac[6]+=bb1.z; ac[7]+=bb1.w;
  ac[8]+=bb2.x; ac[9]+=bb2.y; ac[10]+=bb2.z; ac[11]+=bb2.w;
  ac[12]+=bb3.x; ac[13]+=bb3.y; ac[14]+=bb3.z; ac[15]+=bb3.w;

  if (half == 0){
    uint4 q = make_uint4(pk4f8(ac[0], ac[1], ac[2], ac[3]),
                         pk4f8(ac[4], ac[5], ac[6], ac[7]),
                         pk4f8(ac[8], ac[9], ac[10], ac[11]),
                         pk4f8(ac[12], ac[13], ac[14], ac[15]));
    ((uint4*)(hconv8 + (size_t)i * DIM))[l32] = q;
  }

  const float4* wg4 = (const float4*)(Wg + l32 * 16);
  float4 w0 = wg4[0], w1 = wg4[1], w2 = wg4[2], w3 = wg4[3];
  float gp = ac[0]*w0.x + ac[1]*w0.y + ac[2]*w0.z + ac[3]*w0.w
           + ac[4]*w1.x + ac[5]*w1.y + ac[6]*w1.z + ac[7]*w1.w
           + ac[8]*w2.x + ac[9]*w2.y + ac[10]*w2.z + ac[11]*w2.w
           + ac[12]*w3.x + ac[13]*w3.y + ac[14]*w3.z + ac[15]*w3.w;
  gp = wredSum(gp) * 0.5f;              // both halves contributed identical sums
  if (lane == 0) gate[i] = gp + bg[0];
}

// per-graph sum of exp(gate), LDS-aggregated (~784 global atomics total)
__global__ void k_gsum(const float* __restrict__ gate, const int* __restrict__ batch, float* gsum){
  __shared__ float sm[GQ];
  int t = threadIdx.x, i = blockIdx.x * 512 + t;
  if (t < GQ) sm[t] = 0.f;
  __syncthreads();
  if (i < N_NODES) atomicAdd(&sm[batch[i]], __expf(gate[i]));
  __syncthreads();
  if (t < GQ && sm[t] != 0.f) atomicAdd(&gsum[t], sm[t]);
}

// fused: g = exp(gate)/gsum (written to out_g) + pp[g][c] = sum g_i*hconv[i][c]
__global__ __launch_bounds__(256) void k_pool(const unsigned char* __restrict__ hconv8,
                                              const int* __restrict__ batch,
                                              const float* __restrict__ gate,
                                              const float* __restrict__ gsum,
                                              float* __restrict__ out_g, float* pp){
  __shared__ float gv_s[128];
  __shared__ int b_s[128];
  int t = threadIdx.x;
  int base = blockIdx.x * 128;
  if (t < 128){
    int i = base + t;
    if (i < N_NODES){
      int b = batch[i];
      float gv = __expf(gate[i]) / (gsum[b] + 1e-16f);
      gv_s[t] = gv; b_s[t] = b;
      out_g[i] = gv;
    } else { gv_s[t] = 0.f; b_s[t] = -1; }
  }
  __syncthreads();
  int lim = N_NODES - base; if (lim > 128) lim = 128;
  float ax = 0.f, ay = 0.f;
  int cur = b_s[0];
#pragma unroll 4
  for (int r = 0; r < lim; ++r){
    int b = b_s[r];
    float gv = gv_s[r];
    if (b != cur){
      atomicAdd(&pp[cur * DIM + 2 * t], ax);
      atomicAdd(&pp[cur * DIM + 2 * t + 1], ay);
      ax = ay = 0.f; cur = b;
    }
    unsigned us = *(const unsigned short*)(hconv8 + (size_t)(base + r) * DIM + 2 * t);
    auto p = __builtin_amdgcn_cvt_pk_f32_fp8(us, false);
    ax += gv * p[0];
    ay += gv * p[1];
  }
  if (cur >= 0){
    atomicAdd(&pp[cur * DIM + 2 * t], ax);
    atomicAdd(&pp[cur * DIM + 2 * t + 1], ay);
  }
}

// dst[g][j] = (relu?)(src[g][:] . WT[j][:] + bias[j]) — 128 blocks, wave per column
template<bool RELU>
__global__ void k_headA(const float* __restrict__ src, const float* __restrict__ WT,
                        const float* __restrict__ bias, float* dst){
  __shared__ float sp[GQ * DIM];
  int t = threadIdx.x;
  for (int idx = t; idx < GQ * DIM; idx += 256) sp[idx] = src[idx];
  __syncthreads();
  int wid = t >> 6, lane = t & 63;
  int j = blockIdx.x * 4 + wid;
  const float4* wr = (const float4*)(WT + (size_t)j * DIM);
  float4 w0 = wr[lane * 2], w1 = wr[lane * 2 + 1];
  float bj = bias[j];
#pragma unroll
  for (int g = 0; g < GQ; ++g){
    const float* pg = sp + g * DIM + lane * 8;
    float s = w0.x*pg[0] + w0.y*pg[1] + w0.z*pg[2] + w0.w*pg[3]
            + w1.x*pg[4] + w1.y*pg[5] + w1.z*pg[6] + w1.w*pg[7];
    s = wredSum(s);
    if (lane == 0){
      s += bj;
      if (RELU) s = fmaxf(s, 0.f);
      dst[g * DIM + j] = s;
    }
  }
}

// out[g] = sigmoid(z1[g] . W2 + b2) — 1 block, 8 waves
__global__ void k_headC(const float* __restrict__ z1, const float* __restrict__ W2,
                        const float* __restrict__ b2, float* __restrict__ out){
  int wv = threadIdx.x >> 6, lane = threadIdx.x & 63;
  const float4* zr = (const float4*)(z1 + (size_t)wv * DIM);
  const float4* w4 = (const float4*)W2;
  float s = dot4(zr[lane * 2], w4[lane * 2]) + dot4(zr[lane * 2 + 1], w4[lane * 2 + 1]);
  s = wredSum(s);
  if (lane == 0) out[wv] = 1.f / (1.f + __expf(-(s + b2[0])));
}

// ---------------- launch ----------------
extern "C" void kernel_launch(void* const* d_in, const int* in_sizes, int n_in,
                              void* d_out, int out_size, void* d_ws, size_t ws_size,
                              hipStream_t stream){
  (void)in_sizes; (void)n_in; (void)out_size; (void)ws_size;
  const float* x   = (const float*)d_in[0];
  const int*   ei  = (const int*)d_in[1];
  const int*   bat = (const int*)d_in[2];
  const float* W   = (const float*)d_in[3];
  const float* atS = (const float*)d_in[4];
  const float* atD = (const float*)d_in[5];
  const float* bcv = (const float*)d_in[6];
  const float* Wg  = (const float*)d_in[7];
  const float* bg  = (const float*)d_in[8];
  const float* Wn  = (const float*)d_in[9];
  const float* bn  = (const float*)d_in[10];
  const float* W1  = (const float*)d_in[11];
  const float* b1  = (const float*)d_in[12];
  const float* W2  = (const float*)d_in[13];
  const float* b2  = (const float*)d_in[14];
  float* out = (float*)d_out;
  char* ws = (char*)d_ws;

  unsigned short* x_bf   = (unsigned short*)(ws + OFF_XBF);
  unsigned char*  h8     = (unsigned char*)(ws + OFF_HF8);
  unsigned char*  hconv8 = (unsigned char*)(ws + OFF_HCV8);
  unsigned short* Wt_bf  = (unsigned short*)(ws + OFF_WTBF);
  float* WnT  = (float*)(ws + OFF_WNT);
  float* W1T  = (float*)(ws + OFF_W1T);
  float* ws_s = (float*)(ws + OFF_WSS);
  float* ws_d = (float*)(ws + OFF_WSD);
  float* a_s  = (float*)(ws + OFF_AS);
  float* a_d  = (float*)(ws + OFF_AD);
  float* gate = (float*)(ws + OFF_GATE);
  int* cnt  = (int*)(ws + OFF_CNT);
  int* fill = (int*)(ws + OFF_FILL);
  int* rs   = (int*)(ws + OFF_RS);
  int2* csr2 = (int2*)(ws + OFF_CSR2);
  int* bsum = (int*)(ws + OFF_BSUM);
  float* gsum = (float*)(ws + OFF_GSUM);
  float* pp   = (float*)(ws + OFF_PP);
  float* pool = (float*)(ws + OFF_POOL);
  float* z1   = (float*)(ws + OFF_Z1);

  hipLaunchKernelGGL(k_setup, dim3(NBLK_SCAN + 192), dim3(256), 0, stream,
                     W, atS, atD, Wn, W1, ws_s, ws_d, Wt_bf, WnT, W1T, cnt, fill, gsum, pp);
  hipLaunchKernelGGL(k_cast, dim3(N_PAD / 4), dim3(256), 0, stream,
                     x, ws_s, ws_d, ei, cnt, x_bf, a_s, a_d);
  hipLaunchKernelGGL(k_gemm, dim3(N_PAD / 128, 2), dim3(256), 0, stream, x_bf, Wt_bf, h8);
  hipLaunchKernelGGL(k_scanA, dim3(NBLK_SCAN), dim3(256), 0, stream, cnt, rs, bsum);
  hipLaunchKernelGGL(k_scanC_fill, dim3(NBLK_SCAN), dim3(256), 0, stream, rs, bsum, a_s, csr2);
  hipLaunchKernelGGL(k_fill_edges, dim3((EE + 255) / 256), dim3(256), 0, stream, ei, rs, a_s, fill, csr2);
  hipLaunchKernelGGL(k_edge, dim3(N_NODES / 4), dim3(256), 0, stream,
                     rs, csr2, a_d, h8, bcv, Wg, bg, hconv8, gate);
  hipLaunchKernelGGL(k_gsum, dim3(98), dim3(512), 0, stream, gate, bat, gsum);
  hipLaunchKernelGGL(k_pool, dim3((N_NODES + 127) / 128), dim3(256), 0, stream,
                     hconv8, bat, gate, gsum, out + GQ, pp);
  hipLaunchKernelGGL((k_headA<false>), dim3(128), dim3(256), 0, stream, pp, WnT, bn, pool);
  hipLaunchKernelGGL((k_headA<true>),  dim3(128), dim3(256), 0, stream, pool, W1T, b1, z1);
  hipLaunchKernelGGL(k_headC, dim3(1), dim3(512), 0, stream, z1, W2, b2, out);
}

// Round 7
// 397.178 us; speedup vs baseline: 1.0481x; 1.0481x over previous
//
#include <hip/hip_runtime.h>
#include <stdint.h>

#define N_NODES 50000
#define N_PAD   50048      // 391 * 128
#define GQ      8
#define EE      400000
#define DIM     512
#define NE_TOT  450000     // E + N self loops
#define NBLK_SCAN 196

typedef __attribute__((ext_vector_type(8))) __bf16 bf16x8;
typedef __attribute__((ext_vector_type(4))) float f32x4;

// ---------------- helpers ----------------
__device__ __forceinline__ float bf2f(unsigned short u){ return __uint_as_float(((unsigned)u) << 16); }
__device__ __forceinline__ unsigned short f2bf(float f){
  unsigned u = __float_as_uint(f);
  return (unsigned short)((u + 0x7fffu + ((u >> 16) & 1u)) >> 16);
}
__device__ __forceinline__ unsigned pk2(float lo, float hi){
  return (unsigned)f2bf(lo) | ((unsigned)f2bf(hi) << 16);
}
__device__ __forceinline__ float dot4(float4 a, float4 b){ return a.x*b.x + a.y*b.y + a.z*b.z + a.w*b.w; }
__device__ __forceinline__ float wredSum(float v){
#pragma unroll
  for (int o = 32; o > 0; o >>= 1) v += __shfl_xor(v, o, 64);
  return v;
}
__device__ __forceinline__ int wredSumI(int v){
#pragma unroll
  for (int o = 32; o > 0; o >>= 1) v += __shfl_xor(v, o, 64);
  return v;
}
__device__ __forceinline__ float wredMax(float v){
#pragma unroll
  for (int o = 32; o > 0; o >>= 1) v = fmaxf(v, __shfl_xor(v, o, 64));
  return v;
}
__device__ __forceinline__ void gload_lds16(const void* g, void* l){
  __builtin_amdgcn_global_load_lds((__attribute__((address_space(1))) void*)g,
                                   (__attribute__((address_space(3))) void*)l, 16, 0, 0);
}
// fp8 e4m3 HW codec (self-consistent encode+decode on gfx950)
__device__ __forceinline__ unsigned char f2fp8(float x){
  return (unsigned char)__builtin_amdgcn_cvt_pk_fp8_f32(x, x, 0, false);
}
__device__ __forceinline__ unsigned pk4f8(float a, float b, float c, float d){
  unsigned w = (unsigned)__builtin_amdgcn_cvt_pk_fp8_f32(a, b, 0, false);
  return (unsigned)__builtin_amdgcn_cvt_pk_fp8_f32(c, d, (int)w, true);
}
__device__ __forceinline__ void consumeF8(float* ac, uint2 u, float al){
  auto p0 = __builtin_amdgcn_cvt_pk_f32_fp8(u.x, false);
  auto p1 = __builtin_amdgcn_cvt_pk_f32_fp8(u.x, true);
  auto p2 = __builtin_amdgcn_cvt_pk_f32_fp8(u.y, false);
  auto p3 = __builtin_amdgcn_cvt_pk_f32_fp8(u.y, true);
  ac[0] += al * p0[0]; ac[1] += al * p0[1];
  ac[2] += al * p1[0]; ac[3] += al * p1[1];
  ac[4] += al * p2[0]; ac[5] += al * p2[1];
  ac[6] += al * p3[0]; ac[7] += al * p3[1];
}

// ---------------- workspace layout ----------------
static constexpr size_t AL(size_t x){ return (x + 255) & ~(size_t)255; }
static constexpr size_t OFF_XBF   = 0;
static constexpr size_t OFF_HF8   = OFF_XBF   + AL((size_t)N_PAD * DIM * 2);
static constexpr size_t OFF_HCV8  = OFF_HF8   + AL((size_t)N_PAD * DIM);
static constexpr size_t OFF_WTBF  = OFF_HCV8  + AL((size_t)N_NODES * DIM);
static constexpr size_t OFF_WNT   = OFF_WTBF  + AL((size_t)DIM * DIM * 2);
static constexpr size_t OFF_W1T   = OFF_WNT   + AL((size_t)DIM * DIM * 4);
static constexpr size_t OFF_WSS   = OFF_W1T   + AL((size_t)DIM * DIM * 4);
static constexpr size_t OFF_WSD   = OFF_WSS   + AL((size_t)DIM * 4);
static constexpr size_t OFF_AS    = OFF_WSD   + AL((size_t)DIM * 4);
static constexpr size_t OFF_AD    = OFF_AS    + AL((size_t)N_NODES * 4);
static constexpr size_t OFF_GATE  = OFF_AD    + AL((size_t)N_NODES * 4);
static constexpr size_t OFF_CNT   = OFF_GATE  + AL((size_t)N_NODES * 4);
static constexpr size_t OFF_FILL  = OFF_CNT   + AL((size_t)N_NODES * 4);
static constexpr size_t OFF_RS    = OFF_FILL  + AL((size_t)N_NODES * 4);
static constexpr size_t OFF_CSR2  = OFF_RS    + AL((size_t)(N_NODES + 1) * 4);
static constexpr size_t OFF_BSUM  = OFF_CSR2  + AL((size_t)NE_TOT * 8);
static constexpr size_t OFF_GSUM  = OFF_BSUM  + AL((size_t)NBLK_SCAN * 4);
static constexpr size_t OFF_PP    = OFF_GSUM  + AL((size_t)GQ * 4);
static constexpr size_t OFF_POOL  = OFF_PP    + AL((size_t)GQ * DIM * 4);
static constexpr size_t OFF_Z1    = OFF_POOL  + AL((size_t)GQ * DIM * 4);

// ---------------- kernels ----------------

// fused: init (cnt/fill/gsum/pp) + ws_s/ws_d = W@att_{src,dst} + 3x 512x512 transpose
__global__ void k_setup(const float* __restrict__ W, const float* __restrict__ atS,
                        const float* __restrict__ atD, const float* __restrict__ Wn,
                        const float* __restrict__ W1,
                        float* ws_s, float* ws_d,
                        unsigned short* __restrict__ WtBf, float* __restrict__ WnT,
                        float* __restrict__ W1T,
                        int* cnt, int* fill, float* gsum, float* pp){
  __shared__ float tile[64][65];
  int bx = blockIdx.x;
  if (bx < NBLK_SCAN){
    int i = bx * 256 + threadIdx.x;
    if (i < N_NODES){ cnt[i] = 1; fill[i] = 0; }    // 1 = self-loop slot
    if (i < GQ) gsum[i] = 0.f;
    if (i < GQ * DIM) pp[i] = 0.f;
    if (bx < 128){
      int wid = threadIdx.x >> 6, lane = threadIdx.x & 63;
      int k = bx * 4 + wid;                         // 0..511
      const float4* row = (const float4*)(W + (size_t)k * DIM);
      float4 r0 = row[lane * 2], r1 = row[lane * 2 + 1];
      const float4* s4 = (const float4*)atS;
      const float4* d4 = (const float4*)atD;
      float vs = dot4(r0, s4[lane * 2]) + dot4(r1, s4[lane * 2 + 1]);
      float vd = dot4(r0, d4[lane * 2]) + dot4(r1, d4[lane * 2 + 1]);
      vs = wredSum(vs); vd = wredSum(vd);
      if (lane == 0){ ws_s[k] = vs; ws_d[k] = vd; }
    }
  } else {
    int tb = bx - NBLK_SCAN;
    int y = tb >> 6, bq = tb & 63;
    const float* src = (y == 0) ? W : (y == 1) ? Wn : W1;
    int bi = bq & 7, bj = bq >> 3;
    int r0 = bi * 64, c0 = bj * 64;
#pragma unroll
    for (int ii = 0; ii < 16; ++ii){
      int idx = ii * 256 + threadIdx.x;
      int r = idx >> 6, c = idx & 63;
      tile[r][c] = src[(size_t)(r0 + r) * DIM + c0 + c];
    }
    __syncthreads();
#pragma unroll
    for (int ii = 0; ii < 16; ++ii){
      int idx = ii * 256 + threadIdx.x;
      int cc = idx >> 6, rr = idx & 63;
      float v = tile[rr][cc];
      size_t o = (size_t)(c0 + cc) * DIM + r0 + rr;
      if (y == 0) WtBf[o] = f2bf(v);
      else if (y == 1) WnT[o] = v;
      else W1T[o] = v;
    }
  }
}

// cast x -> bf16 (zero pad rows), a_s/a_d per row, + fused edge histogram
__global__ __launch_bounds__(256) void k_cast(const float* __restrict__ x,
                                              const float* __restrict__ ws_s,
                                              const float* __restrict__ ws_d,
                                              const int* __restrict__ ei, int* cnt,
                                              unsigned short* __restrict__ x_bf,
                                              float* __restrict__ a_s, float* __restrict__ a_d){
  int gt = blockIdx.x * 256 + threadIdx.x;
  if (gt < EE) atomicAdd(&cnt[ei[EE + gt]], 1);
  int wid = threadIdx.x >> 6, lane = threadIdx.x & 63;
  size_t i = (size_t)blockIdx.x * 4 + wid;
  if (i >= N_PAD) return;
  unsigned short* orow = x_bf + i * DIM;
  if (i >= N_NODES){
    ((uint4*)orow)[lane] = make_uint4(0, 0, 0, 0);
    return;
  }
  const float4* xr = (const float4*)(x + i * DIM);
  float4 v0 = xr[lane * 2], v1 = xr[lane * 2 + 1];
  ((uint4*)orow)[lane] = make_uint4(pk2(v0.x, v0.y), pk2(v0.z, v0.w), pk2(v1.x, v1.y), pk2(v1.z, v1.w));
  const float4* s4 = (const float4*)ws_s;
  const float4* d4 = (const float4*)ws_d;
  float vs = dot4(v0, s4[lane * 2]) + dot4(v1, s4[lane * 2 + 1]);
  float vd = dot4(v0, d4[lane * 2]) + dot4(v1, d4[lane * 2 + 1]);
  vs = wredSum(vs); vd = wredSum(vd);
  if (lane == 0){ a_s[i] = vs; a_d[i] = vd; }
}

// h = x_bf @ W (Bt = W^T, bf16). 128x256 strip tile, 16x16x32 MFMA, XOR bank swizzle.
// Epilogue stores h as fp8 e4m3 (halves k_edge's gather bytes; error budget ok).
__global__ __launch_bounds__(256, 2) void k_gemm(const unsigned short* __restrict__ A,
                                                 const unsigned short* __restrict__ Bt,
                                                 unsigned char* __restrict__ H8){
  __shared__ unsigned short As[128 * 32];   // 8 KB
  __shared__ unsigned short Bs[256 * 32];   // 16 KB
  const int tid = threadIdx.x;
  const int wid = tid >> 6, lane = tid & 63, quad = lane >> 4, l16 = lane & 15;
  const int m0 = blockIdx.x * 128, n0 = blockIdx.y * 256;
  const int wm = (wid & 1) * 64, wn = (wid >> 1) * 128;
  const int qa = quad ^ ((l16 >> 1) & 3);           // swizzled chunk for reads
  f32x4 acc[4][8] = {};
  for (int kt = 0; kt < 16; ++kt){
    const int k0 = kt * 32;
    __syncthreads();
#pragma unroll
    for (int r = 0; r < 2; ++r){                    // A: 512 16B-chunks
      int p = r * 256 + tid;
      int mm = p >> 2;
      int qg = (p & 3) ^ ((mm >> 1) & 3);
      gload_lds16(A + (size_t)(m0 + mm) * DIM + k0 + qg * 8,
                  As + (size_t)(r * 256 + wid * 64) * 8);
    }
#pragma unroll
    for (int r = 0; r < 4; ++r){                    // B: 1024 16B-chunks
      int p = r * 256 + tid;
      int mm = p >> 2;
      int qg = (p & 3) ^ ((mm >> 1) & 3);
      gload_lds16(Bt + (size_t)(n0 + mm) * DIM + k0 + qg * 8,
                  Bs + (size_t)(r * 256 + wid * 64) * 8);
    }
    __syncthreads();
    bf16x8 af[4], bfr[8];
#pragma unroll
    for (int f = 0; f < 4; ++f)
      af[f]  = *(const bf16x8*)(As + (wm + f * 16 + l16) * 32 + qa * 8);
#pragma unroll
    for (int f = 0; f < 8; ++f)
      bfr[f] = *(const bf16x8*)(Bs + (wn + f * 16 + l16) * 32 + qa * 8);
#pragma unroll
    for (int fm = 0; fm < 4; ++fm)
#pragma unroll
      for (int fn = 0; fn < 8; ++fn)
        acc[fm][fn] = __builtin_amdgcn_mfma_f32_16x16x32_bf16(af[fm], bfr[fn], acc[fm][fn], 0, 0, 0);
  }
#pragma unroll
  for (int fm = 0; fm < 4; ++fm){
#pragma unroll
    for (int r = 0; r < 4; ++r){
      size_t gro = (size_t)(m0 + wm + fm * 16 + quad * 4 + r) * DIM + n0 + wn + l16;
#pragma unroll
      for (int fn = 0; fn < 8; ++fn)
        H8[gro + fn * 16] = f2fp8(acc[fm][fn][r]);
    }
  }
}

__global__ void k_scanA(const int* __restrict__ cnt, int* rs, int* bsum){
  __shared__ int sm[256];
  int t = threadIdx.x, i = blockIdx.x * 256 + t;
  int v = (i < N_NODES) ? cnt[i] : 0;
  sm[t] = v; __syncthreads();
#pragma unroll
  for (int off = 1; off < 256; off <<= 1){
    int nv = (t >= off) ? sm[t - off] : 0;
    __syncthreads();
    sm[t] += nv;
    __syncthreads();
  }
  if (i < N_NODES) rs[i] = sm[t] - v;
  if (t == 255) bsum[blockIdx.x] = sm[255];
}

// fused: add block-prefix of bsum, write self-loop csr slot (src=i, a_s[i])
__global__ void k_scanC_fill(int* rs, const int* __restrict__ bsum,
                             const float* __restrict__ a_s, int2* csr2){
  __shared__ int sm4[4];
  int t = threadIdx.x;
  int acc = 0;
  for (int k = t; k < blockIdx.x; k += 256) acc += bsum[k];
  acc = wredSumI(acc);
  if ((t & 63) == 0) sm4[t >> 6] = acc;
  __syncthreads();
  int boff = sm4[0] + sm4[1] + sm4[2] + sm4[3];
  int i = blockIdx.x * 256 + t;
  if (i < N_NODES){
    int v = rs[i] + boff;
    rs[i] = v;
    csr2[v] = make_int2(i, __float_as_int(a_s[i]));  // self-loop at slot 0
  }
  if (i == 0) rs[N_NODES] = NE_TOT;
}

__global__ void k_fill_edges(const int* __restrict__ ei, const int* __restrict__ rs,
                             const float* __restrict__ a_s, int* fill, int2* csr2){
  int e = blockIdx.x * 256 + threadIdx.x;
  if (e < EE){
    int s = ei[e], d = ei[EE + e];
    int p = atomicAdd(&fill[d], 1);
    csr2[rs[d] + 1 + p] = make_int2(s, __float_as_int(a_s[s]));
  }
}

// one wave per dst node (round-5 shape, VGPR-lean), 10-deep pipelined fp8 gather.
// Lesson (r6): k_edge is MLP-bound; occupancy x pipeline-depth sets achieved BW.
// Spending VGPRs on wider accumulators dropped occupancy 35->20% and cost 1.6x.
// NOTE: no per-node contended global atomics (round-3: 50k atomics on 8 floats = +570us)
__global__ __launch_bounds__(256) void k_edge(const int* __restrict__ rs, const int2* __restrict__ csr2,
                                              const float* __restrict__ a_d,
                                              const unsigned char* __restrict__ h8,
                                              const float* __restrict__ bconv,
                                              const float* __restrict__ Wg, const float* __restrict__ bg,
                                              unsigned char* __restrict__ hconv8, float* __restrict__ gate){
  int wid = threadIdx.x >> 6, lane = threadIdx.x & 63;
  int i = blockIdx.x * 4 + wid;
  if (i >= N_NODES) return;
  int r0 = rs[i], r1 = rs[i + 1];
  int deg = r1 - r0;
  float adi = a_d[i];
  float ac[8] = {0.f, 0.f, 0.f, 0.f, 0.f, 0.f, 0.f, 0.f};

  if (deg <= 128){
    int s_l0 = 0, s_l1 = 0;
    float e_a = -__builtin_inff(), e_b = -__builtin_inff();
    if (lane < deg){
      int2 c = csr2[r0 + lane]; s_l0 = c.x;
      float e = __int_as_float(c.y) + adi; e_a = (e > 0.f) ? e : 0.2f * e;
    }
    if (64 + lane < deg){
      int2 c = csr2[r0 + 64 + lane]; s_l1 = c.x;
      float e = __int_as_float(c.y) + adi; e_b = (e > 0.f) ? e : 0.2f * e;
    }
    float mx = wredMax(fmaxf(e_a, e_b));
    float x0 = (lane < deg) ? __expf(e_a - mx) : 0.f;
    float x1 = (64 + lane < deg) ? __expf(e_b - mx) : 0.f;
    float inv = 1.f / (wredSum(x0 + x1) + 1e-16f);

    auto FETCH = [&](int jj, uint2& u, float& al){
      int s  = __shfl((jj < 64) ? s_l0 : s_l1, jj & 63);
      al = __shfl((jj < 64) ? x0 : x1, jj & 63) * inv;
      u = *((const uint2*)(h8 + (size_t)s * DIM) + lane);
    };
    uint2 u0, u1, u2, u3, u4, u5, u6, u7, u8, u9;
    float f0, f1, f2, f3, f4, f5, f6, f7, f8, f9;
    if (deg > 0) FETCH(0, u0, f0);
    if (deg > 1) FETCH(1, u1, f1);
    if (deg > 2) FETCH(2, u2, f2);
    if (deg > 3) FETCH(3, u3, f3);
    if (deg > 4) FETCH(4, u4, f4);
    if (deg > 5) FETCH(5, u5, f5);
    if (deg > 6) FETCH(6, u6, f6);
    if (deg > 7) FETCH(7, u7, f7);
    if (deg > 8) FETCH(8, u8, f8);
    if (deg > 9) FETCH(9, u9, f9);
    for (int j = 0; j < deg; j += 10){
      consumeF8(ac, u0, f0); if (j + 10 < deg) FETCH(j + 10, u0, f0);
      if (j + 1 >= deg) break;
      consumeF8(ac, u1, f1); if (j + 11 < deg) FETCH(j + 11, u1, f1);
      if (j + 2 >= deg) break;
      consumeF8(ac, u2, f2); if (j + 12 < deg) FETCH(j + 12, u2, f2);
      if (j + 3 >= deg) break;
      consumeF8(ac, u3, f3); if (j + 13 < deg) FETCH(j + 13, u3, f3);
      if (j + 4 >= deg) break;
      consumeF8(ac, u4, f4); if (j + 14 < deg) FETCH(j + 14, u4, f4);
      if (j + 5 >= deg) break;
      consumeF8(ac, u5, f5); if (j + 15 < deg) FETCH(j + 15, u5, f5);
      if (j + 6 >= deg) break;
      consumeF8(ac, u6, f6); if (j + 16 < deg) FETCH(j + 16, u6, f6);
      if (j + 7 >= deg) break;
      consumeF8(ac, u7, f7); if (j + 17 < deg) FETCH(j + 17, u7, f7);
      if (j + 8 >= deg) break;
      consumeF8(ac, u8, f8); if (j + 18 < deg) FETCH(j + 18, u8, f8);
      if (j + 9 >= deg) break;
      consumeF8(ac, u9, f9); if (j + 19 < deg) FETCH(j + 19, u9, f9);
    }
  } else {
    // generic fallback (vanishingly rare)
    float mx = -__builtin_inff();
    for (int j = r0 + lane; j < r1; j += 64){
      float e = __int_as_float(csr2[j].y) + adi; e = (e > 0.f) ? e : 0.2f * e;
      mx = fmaxf(mx, e);
    }
    mx = wredMax(mx);
    float ssum = 0.f;
    for (int j = r0 + lane; j < r1; j += 64){
      float e = __int_as_float(csr2[j].y) + adi; e = (e > 0.f) ? e : 0.2f * e;
      ssum += __expf(e - mx);
    }
    float inv = 1.f / (wredSum(ssum) + 1e-16f);
    for (int j = r0; j < r1; ++j){
      int2 c = csr2[j];
      float e = __int_as_float(c.y) + adi; e = (e > 0.f) ? e : 0.2f * e;
      float al = __expf(e - mx) * inv;
      uint2 u = *((const uint2*)(h8 + (size_t)c.x * DIM) + lane);
      consumeF8(ac, u, al);
    }
  }

  float4 bc0 = ((const float4*)bconv)[lane * 2];
  float4 bc1 = ((const float4*)bconv)[lane * 2 + 1];
  ac[0] += bc0.x; ac[1] += bc0.y; ac[2] += bc0.z; ac[3] += bc0.w;
  ac[4] += bc1.x; ac[5] += bc1.y; ac[6] += bc1.z; ac[7] += bc1.w;
  unsigned w0 = pk4f8(ac[0], ac[1], ac[2], ac[3]);
  unsigned w1 = pk4f8(ac[4], ac[5], ac[6], ac[7]);
  ((uint2*)(hconv8 + (size_t)i * DIM))[lane] = make_uint2(w0, w1);
  float4 wg0 = ((const float4*)Wg)[lane * 2];
  float4 wg1 = ((const float4*)Wg)[lane * 2 + 1];
  float gp = ac[0]*wg0.x + ac[1]*wg0.y + ac[2]*wg0.z + ac[3]*wg0.w
           + ac[4]*wg1.x + ac[5]*wg1.y + ac[6]*wg1.z + ac[7]*wg1.w;
  gp = wredSum(gp);
  if (lane == 0) gate[i] = gp + bg[0];
}

// per-graph sum of exp(gate), LDS-aggregated (~784 global atomics total)
__global__ void k_gsum(const float* __restrict__ gate, const int* __restrict__ batch, float* gsum){
  __shared__ float sm[GQ];
  int t = threadIdx.x, i = blockIdx.x * 512 + t;
  if (t < GQ) sm[t] = 0.f;
  __syncthreads();
  if (i < N_NODES) atomicAdd(&sm[batch[i]], __expf(gate[i]));
  __syncthreads();
  if (t < GQ && sm[t] != 0.f) atomicAdd(&gsum[t], sm[t]);
}

// fused: g = exp(gate)/gsum (written to out_g) + pp[g][c] = sum g_i*hconv[i][c]
__global__ __launch_bounds__(256) void k_pool(const unsigned char* __restrict__ hconv8,
                                              const int* __restrict__ batch,
                                              const float* __restrict__ gate,
                                              const float* __restrict__ gsum,
                                              float* __restrict__ out_g, float* pp){
  __shared__ float gv_s[128];
  __shared__ int b_s[128];
  int t = threadIdx.x;
  int base = blockIdx.x * 128;
  if (t < 128){
    int i = base + t;
    if (i < N_NODES){
      int b = batch[i];
      float gv = __expf(gate[i]) / (gsum[b] + 1e-16f);
      gv_s[t] = gv; b_s[t] = b;
      out_g[i] = gv;
    } else { gv_s[t] = 0.f; b_s[t] = -1; }
  }
  __syncthreads();
  int lim = N_NODES - base; if (lim > 128) lim = 128;
  float ax = 0.f, ay = 0.f;
  int cur = b_s[0];
#pragma unroll 4
  for (int r = 0; r < lim; ++r){
    int b = b_s[r];
    float gv = gv_s[r];
    if (b != cur){
      atomicAdd(&pp[cur * DIM + 2 * t], ax);
      atomicAdd(&pp[cur * DIM + 2 * t + 1], ay);
      ax = ay = 0.f; cur = b;
    }
    unsigned us = *(const unsigned short*)(hconv8 + (size_t)(base + r) * DIM + 2 * t);
    auto p = __builtin_amdgcn_cvt_pk_f32_fp8(us, false);
    ax += gv * p[0];
    ay += gv * p[1];
  }
  if (cur >= 0){
    atomicAdd(&pp[cur * DIM + 2 * t], ax);
    atomicAdd(&pp[cur * DIM + 2 * t + 1], ay);
  }
}

// dst[g][j] = (relu?)(src[g][:] . WT[j][:] + bias[j]) — 128 blocks, wave per column
template<bool RELU>
__global__ void k_headA(const float* __restrict__ src, const float* __restrict__ WT,
                        const float* __restrict__ bias, float* dst){
  __shared__ float sp[GQ * DIM];
  int t = threadIdx.x;
  for (int idx = t; idx < GQ * DIM; idx += 256) sp[idx] = src[idx];
  __syncthreads();
  int wid = t >> 6, lane = t & 63;
  int j = blockIdx.x * 4 + wid;
  const float4* wr = (const float4*)(WT + (size_t)j * DIM);
  float4 w0 = wr[lane * 2], w1 = wr[lane * 2 + 1];
  float bj = bias[j];
#pragma unroll
  for (int g = 0; g < GQ; ++g){
    const float* pg = sp + g * DIM + lane * 8;
    float s = w0.x*pg[0] + w0.y*pg[1] + w0.z*pg[2] + w0.w*pg[3]
            + w1.x*pg[4] + w1.y*pg[5] + w1.z*pg[6] + w1.w*pg[7];
    s = wredSum(s);
    if (lane == 0){
      s += bj;
      if (RELU) s = fmaxf(s, 0.f);
      dst[g * DIM + j] = s;
    }
  }
}

// out[g] = sigmoid(z1[g] . W2 + b2) — 1 block, 8 waves
__global__ void k_headC(const float* __restrict__ z1, const float* __restrict__ W2,
                        const float* __restrict__ b2, float* __restrict__ out){
  int wv = threadIdx.x >> 6, lane = threadIdx.x & 63;
  const float4* zr = (const float4*)(z1 + (size_t)wv * DIM);
  const float4* w4 = (const float4*)W2;
  float s = dot4(zr[lane * 2], w4[lane * 2]) + dot4(zr[lane * 2 + 1], w4[lane * 2 + 1]);
  s = wredSum(s);
  if (lane == 0) out[wv] = 1.f / (1.f + __expf(-(s + b2[0])));
}

// ---------------- launch ----------------
extern "C" void kernel_launch(void* const* d_in, const int* in_sizes, int n_in,
                              void* d_out, int out_size, void* d_ws, size_t ws_size,
                              hipStream_t stream){
  (void)in_sizes; (void)n_in; (void)out_size; (void)ws_size;
  const float* x   = (const float*)d_in[0];
  const int*   ei  = (const int*)d_in[1];
  const int*   bat = (const int*)d_in[2];
  const float* W   = (const float*)d_in[3];
  const float* atS = (const float*)d_in[4];
  const float* atD = (const float*)d_in[5];
  const float* bcv = (const float*)d_in[6];
  const float* Wg  = (const float*)d_in[7];
  const float* bg  = (const float*)d_in[8];
  const float* Wn  = (const float*)d_in[9];
  const float* bn  = (const float*)d_in[10];
  const float* W1  = (const float*)d_in[11];
  const float* b1  = (const float*)d_in[12];
  const float* W2  = (const float*)d_in[13];
  const float* b2  = (const float*)d_in[14];
  float* out = (float*)d_out;
  char* ws = (char*)d_ws;

  unsigned short* x_bf   = (unsigned short*)(ws + OFF_XBF);
  unsigned char*  h8     = (unsigned char*)(ws + OFF_HF8);
  unsigned char*  hconv8 = (unsigned char*)(ws + OFF_HCV8);
  unsigned short* Wt_bf  = (unsigned short*)(ws + OFF_WTBF);
  float* WnT  = (float*)(ws + OFF_WNT);
  float* W1T  = (float*)(ws + OFF_W1T);
  float* ws_s = (float*)(ws + OFF_WSS);
  float* ws_d = (float*)(ws + OFF_WSD);
  float* a_s  = (float*)(ws + OFF_AS);
  float* a_d  = (float*)(ws + OFF_AD);
  float* gate = (float*)(ws + OFF_GATE);
  int* cnt  = (int*)(ws + OFF_CNT);
  int* fill = (int*)(ws + OFF_FILL);
  int* rs   = (int*)(ws + OFF_RS);
  int2* csr2 = (int2*)(ws + OFF_CSR2);
  int* bsum = (int*)(ws + OFF_BSUM);
  float* gsum = (float*)(ws + OFF_GSUM);
  float* pp   = (float*)(ws + OFF_PP);
  float* pool = (float*)(ws + OFF_POOL);
  float* z1   = (float*)(ws + OFF_Z1);

  hipLaunchKernelGGL(k_setup, dim3(NBLK_SCAN + 192), dim3(256), 0, stream,
                     W, atS, atD, Wn, W1, ws_s, ws_d, Wt_bf, WnT, W1T, cnt, fill, gsum, pp);
  hipLaunchKernelGGL(k_cast, dim3(N_PAD / 4), dim3(256), 0, stream,
                     x, ws_s, ws_d, ei, cnt, x_bf, a_s, a_d);
  hipLaunchKernelGGL(k_gemm, dim3(N_PAD / 128, 2), dim3(256), 0, stream, x_bf, Wt_bf, h8);
  hipLaunchKernelGGL(k_scanA, dim3(NBLK_SCAN), dim3(256), 0, stream, cnt, rs, bsum);
  hipLaunchKernelGGL(k_scanC_fill, dim3(NBLK_SCAN), dim3(256), 0, stream, rs, bsum, a_s, csr2);
  hipLaunchKernelGGL(k_fill_edges, dim3((EE + 255) / 256), dim3(256), 0, stream, ei, rs, a_s, fill, csr2);
  hipLaunchKernelGGL(k_edge, dim3(N_NODES / 4), dim3(256), 0, stream,
                     rs, csr2, a_d, h8, bcv, Wg, bg, hconv8, gate);
  hipLaunchKernelGGL(k_gsum, dim3(98), dim3(512), 0, stream, gate, bat, gsum);
  hipLaunchKernelGGL(k_pool, dim3((N_NODES + 127) / 128), dim3(256), 0, stream,
                     hconv8, bat, gate, gsum, out + GQ, pp);
  hipLaunchKernelGGL((k_headA<false>), dim3(128), dim3(256), 0, stream, pp, WnT, bn, pool);
  hipLaunchKernelGGL((k_headA<true>),  dim3(128), dim3(256), 0, stream, pool, W1T, b1, z1);
  hipLaunchKernelGGL(k_headC, dim3(1), dim3(512), 0, stream, z1, W2, b2, out);
}

// Round 8
// 373.831 us; speedup vs baseline: 1.1136x; 1.0625x over previous
//
#include <hip/hip_runtime.h>
#include <stdint.h>

#define N_NODES 50000
#define N_PAD   50048      // 391 * 128
#define GQ      8
#define EE      400000
#define DIM     512
#define CAPE    128        // per-node edge-slot capacity (Poisson(8)+1 max ~35)
#define NBLK_SCAN 196

typedef __attribute__((ext_vector_type(8))) __bf16 bf16x8;
typedef __attribute__((ext_vector_type(4))) float f32x4;

// ---------------- helpers ----------------
__device__ __forceinline__ unsigned short f2bf(float f){
  unsigned u = __float_as_uint(f);
  return (unsigned short)((u + 0x7fffu + ((u >> 16) & 1u)) >> 16);
}
__device__ __forceinline__ unsigned pk2(float lo, float hi){
  return (unsigned)f2bf(lo) | ((unsigned)f2bf(hi) << 16);
}
__device__ __forceinline__ float dot4(float4 a, float4 b){ return a.x*b.x + a.y*b.y + a.z*b.z + a.w*b.w; }
__device__ __forceinline__ float wredSum(float v){
#pragma unroll
  for (int o = 32; o > 0; o >>= 1) v += __shfl_xor(v, o, 64);
  return v;
}
__device__ __forceinline__ float wredMax(float v){
#pragma unroll
  for (int o = 32; o > 0; o >>= 1) v = fmaxf(v, __shfl_xor(v, o, 64));
  return v;
}
__device__ __forceinline__ void gload_lds16(const void* g, void* l){
  __builtin_amdgcn_global_load_lds((__attribute__((address_space(1))) void*)g,
                                   (__attribute__((address_space(3))) void*)l, 16, 0, 0);
}
// fp8 e4m3 HW codec (self-consistent encode+decode on gfx950)
__device__ __forceinline__ unsigned char f2fp8(float x){
  return (unsigned char)__builtin_amdgcn_cvt_pk_fp8_f32(x, x, 0, false);
}
__device__ __forceinline__ unsigned pk4f8(float a, float b, float c, float d){
  unsigned w = (unsigned)__builtin_amdgcn_cvt_pk_fp8_f32(a, b, 0, false);
  return (unsigned)__builtin_amdgcn_cvt_pk_fp8_f32(c, d, (int)w, true);
}
__device__ __forceinline__ void consumeF8(float* ac, uint2 u, float al){
  auto p0 = __builtin_amdgcn_cvt_pk_f32_fp8(u.x, false);
  auto p1 = __builtin_amdgcn_cvt_pk_f32_fp8(u.x, true);
  auto p2 = __builtin_amdgcn_cvt_pk_f32_fp8(u.y, false);
  auto p3 = __builtin_amdgcn_cvt_pk_f32_fp8(u.y, true);
  ac[0] += al * p0[0]; ac[1] += al * p0[1];
  ac[2] += al * p1[0]; ac[3] += al * p1[1];
  ac[4] += al * p2[0]; ac[5] += al * p2[1];
  ac[6] += al * p3[0]; ac[7] += al * p3[1];
}

// ---------------- workspace layout ----------------
static constexpr size_t AL(size_t x){ return (x + 255) & ~(size_t)255; }
static constexpr size_t OFF_XBF   = 0;
static constexpr size_t OFF_HF8   = OFF_XBF   + AL((size_t)N_PAD * DIM * 2);
static constexpr size_t OFF_HCV8  = OFF_HF8   + AL((size_t)N_PAD * DIM);
static constexpr size_t OFF_CAP   = OFF_HCV8  + AL((size_t)N_NODES * DIM);
static constexpr size_t OFF_WTBF  = OFF_CAP   + AL((size_t)N_NODES * CAPE * 8);
static constexpr size_t OFF_WNT   = OFF_WTBF  + AL((size_t)DIM * DIM * 2);
static constexpr size_t OFF_W1T   = OFF_WNT   + AL((size_t)DIM * DIM * 4);
static constexpr size_t OFF_WSS   = OFF_W1T   + AL((size_t)DIM * DIM * 4);
static constexpr size_t OFF_WSD   = OFF_WSS   + AL((size_t)DIM * 4);
static constexpr size_t OFF_AS    = OFF_WSD   + AL((size_t)DIM * 4);
static constexpr size_t OFF_AD    = OFF_AS    + AL((size_t)N_NODES * 4);
static constexpr size_t OFF_GATE  = OFF_AD    + AL((size_t)N_NODES * 4);
static constexpr size_t OFF_CNT   = OFF_GATE  + AL((size_t)N_NODES * 4);
static constexpr size_t OFF_GSUM  = OFF_CNT   + AL((size_t)N_NODES * 4);
static constexpr size_t OFF_PP    = OFF_GSUM  + AL((size_t)GQ * 4);
static constexpr size_t OFF_POOL  = OFF_PP    + AL((size_t)GQ * DIM * 4);
static constexpr size_t OFF_Z1    = OFF_POOL  + AL((size_t)GQ * DIM * 4);

// ---------------- kernels ----------------

// fused: init (cnt/gsum/pp) + ws_s/ws_d = W@att_{src,dst} + 3x 512x512 transpose
__global__ void k_setup(const float* __restrict__ W, const float* __restrict__ atS,
                        const float* __restrict__ atD, const float* __restrict__ Wn,
                        const float* __restrict__ W1,
                        float* ws_s, float* ws_d,
                        unsigned short* __restrict__ WtBf, float* __restrict__ WnT,
                        float* __restrict__ W1T,
                        int* cnt, float* gsum, float* pp){
  __shared__ float tile[64][65];
  int bx = blockIdx.x;
  if (bx < NBLK_SCAN){
    int i = bx * 256 + threadIdx.x;
    if (i < N_NODES) cnt[i] = 1;                    // slot 0 = self-loop
    if (i < GQ) gsum[i] = 0.f;
    if (i < GQ * DIM) pp[i] = 0.f;
    if (bx < 128){
      int wid = threadIdx.x >> 6, lane = threadIdx.x & 63;
      int k = bx * 4 + wid;                         // 0..511
      const float4* row = (const float4*)(W + (size_t)k * DIM);
      float4 r0 = row[lane * 2], r1 = row[lane * 2 + 1];
      const float4* s4 = (const float4*)atS;
      const float4* d4 = (const float4*)atD;
      float vs = dot4(r0, s4[lane * 2]) + dot4(r1, s4[lane * 2 + 1]);
      float vd = dot4(r0, d4[lane * 2]) + dot4(r1, d4[lane * 2 + 1]);
      vs = wredSum(vs); vd = wredSum(vd);
      if (lane == 0){ ws_s[k] = vs; ws_d[k] = vd; }
    }
  } else {
    int tb = bx - NBLK_SCAN;
    int y = tb >> 6, bq = tb & 63;
    const float* src = (y == 0) ? W : (y == 1) ? Wn : W1;
    int bi = bq & 7, bj = bq >> 3;
    int r0 = bi * 64, c0 = bj * 64;
#pragma unroll
    for (int ii = 0; ii < 16; ++ii){
      int idx = ii * 256 + threadIdx.x;
      int r = idx >> 6, c = idx & 63;
      tile[r][c] = src[(size_t)(r0 + r) * DIM + c0 + c];
    }
    __syncthreads();
#pragma unroll
    for (int ii = 0; ii < 16; ++ii){
      int idx = ii * 256 + threadIdx.x;
      int cc = idx >> 6, rr = idx & 63;
      float v = tile[rr][cc];
      size_t o = (size_t)(c0 + cc) * DIM + r0 + rr;
      if (y == 0) WtBf[o] = f2bf(v);
      else if (y == 1) WnT[o] = v;
      else W1T[o] = v;
    }
  }
}

// cast x -> bf16 (zero pad rows), a_s/a_d per row, write self-loop cap slot 0
__global__ __launch_bounds__(256) void k_cast(const float* __restrict__ x,
                                              const float* __restrict__ ws_s,
                                              const float* __restrict__ ws_d,
                                              unsigned short* __restrict__ x_bf,
                                              float* __restrict__ a_s, float* __restrict__ a_d,
                                              int2* __restrict__ cap){
  int wid = threadIdx.x >> 6, lane = threadIdx.x & 63;
  size_t i = (size_t)blockIdx.x * 4 + wid;
  if (i >= N_PAD) return;
  unsigned short* orow = x_bf + i * DIM;
  if (i >= N_NODES){
    ((uint4*)orow)[lane] = make_uint4(0, 0, 0, 0);
    return;
  }
  const float4* xr = (const float4*)(x + i * DIM);
  float4 v0 = xr[lane * 2], v1 = xr[lane * 2 + 1];
  ((uint4*)orow)[lane] = make_uint4(pk2(v0.x, v0.y), pk2(v0.z, v0.w), pk2(v1.x, v1.y), pk2(v1.z, v1.w));
  const float4* s4 = (const float4*)ws_s;
  const float4* d4 = (const float4*)ws_d;
  float vs = dot4(v0, s4[lane * 2]) + dot4(v1, s4[lane * 2 + 1]);
  float vd = dot4(v0, d4[lane * 2]) + dot4(v1, d4[lane * 2 + 1]);
  vs = wredSum(vs); vd = wredSum(vd);
  if (lane == 0){
    a_s[i] = vs; a_d[i] = vd;
    cap[i * CAPE] = make_int2((int)i, __float_as_int(vs));   // self-loop, slot 0
  }
}

// append edges into fixed-capacity per-dst rows (no prefix scan needed)
__global__ void k_fill(const int* __restrict__ ei, const float* __restrict__ a_s,
                       int* cnt, int2* __restrict__ cap){
  int e = blockIdx.x * 256 + threadIdx.x;
  if (e < EE){
    int s = ei[e], d = ei[EE + e];
    int p = atomicAdd(&cnt[d], 1);
    if (p < CAPE) cap[(size_t)d * CAPE + p] = make_int2(s, __float_as_int(a_s[s]));
  }
}

// h = x_bf @ W (Bt = W^T, bf16). 128x256 strip tile, 16x16x32 MFMA, XOR bank swizzle.
// Epilogue stores h as fp8 e4m3 (halves k_edge's gather bytes; error budget ok).
__global__ __launch_bounds__(256, 2) void k_gemm(const unsigned short* __restrict__ A,
                                                 const unsigned short* __restrict__ Bt,
                                                 unsigned char* __restrict__ H8){
  __shared__ unsigned short As[128 * 32];   // 8 KB
  __shared__ unsigned short Bs[256 * 32];   // 16 KB
  const int tid = threadIdx.x;
  const int wid = tid >> 6, lane = tid & 63, quad = lane >> 4, l16 = lane & 15;
  const int m0 = blockIdx.x * 128, n0 = blockIdx.y * 256;
  const int wm = (wid & 1) * 64, wn = (wid >> 1) * 128;
  const int qa = quad ^ ((l16 >> 1) & 3);           // swizzled chunk for reads
  f32x4 acc[4][8] = {};
  for (int kt = 0; kt < 16; ++kt){
    const int k0 = kt * 32;
    __syncthreads();
#pragma unroll
    for (int r = 0; r < 2; ++r){                    // A: 512 16B-chunks
      int p = r * 256 + tid;
      int mm = p >> 2;
      int qg = (p & 3) ^ ((mm >> 1) & 3);
      gload_lds16(A + (size_t)(m0 + mm) * DIM + k0 + qg * 8,
                  As + (size_t)(r * 256 + wid * 64) * 8);
    }
#pragma unroll
    for (int r = 0; r < 4; ++r){                    // B: 1024 16B-chunks
      int p = r * 256 + tid;
      int mm = p >> 2;
      int qg = (p & 3) ^ ((mm >> 1) & 3);
      gload_lds16(Bt + (size_t)(n0 + mm) * DIM + k0 + qg * 8,
                  Bs + (size_t)(r * 256 + wid * 64) * 8);
    }
    __syncthreads();
    bf16x8 af[4], bfr[8];
#pragma unroll
    for (int f = 0; f < 4; ++f)
      af[f]  = *(const bf16x8*)(As + (wm + f * 16 + l16) * 32 + qa * 8);
#pragma unroll
    for (int f = 0; f < 8; ++f)
      bfr[f] = *(const bf16x8*)(Bs + (wn + f * 16 + l16) * 32 + qa * 8);
#pragma unroll
    for (int fm = 0; fm < 4; ++fm)
#pragma unroll
      for (int fn = 0; fn < 8; ++fn)
        acc[fm][fn] = __builtin_amdgcn_mfma_f32_16x16x32_bf16(af[fm], bfr[fn], acc[fm][fn], 0, 0, 0);
  }
#pragma unroll
  for (int fm = 0; fm < 4; ++fm){
#pragma unroll
    for (int r = 0; r < 4; ++r){
      size_t gro = (size_t)(m0 + wm + fm * 16 + quad * 4 + r) * DIM + n0 + wn + l16;
#pragma unroll
      for (int fn = 0; fn < 8; ++fn)
        H8[gro + fn * 16] = f2fp8(acc[fm][fn][r]);
    }
  }
}

// one wave per dst node (r5 shape: depth-8 pipeline, VGPR<=64 => 8 waves/SIMD).
// Lessons: time ∝ 1/resident-waves (r6/r7: +VGPR regressed 1.3-1.6x); no contended
// global atomics (r3: +570us). Capacity rows: deg<=64 single-batch fast path.
__global__ __launch_bounds__(256) void k_edge(const int* __restrict__ cnt, const int2* __restrict__ cap,
                                              const float* __restrict__ a_d,
                                              const unsigned char* __restrict__ h8,
                                              const float* __restrict__ bconv,
                                              const float* __restrict__ Wg, const float* __restrict__ bg,
                                              unsigned char* __restrict__ hconv8, float* __restrict__ gate){
  int wid = threadIdx.x >> 6, lane = threadIdx.x & 63;
  int i = blockIdx.x * 4 + wid;
  if (i >= N_NODES) return;
  int deg = cnt[i]; if (deg > CAPE) deg = CAPE;
  const int2* row = cap + (size_t)i * CAPE;
  float adi = a_d[i];
  float ac[8] = {0.f, 0.f, 0.f, 0.f, 0.f, 0.f, 0.f, 0.f};

  if (deg <= 64){
    int s_l = 0;
    float e_a = -__builtin_inff();
    if (lane < deg){
      int2 c = row[lane]; s_l = c.x;
      float e = __int_as_float(c.y) + adi; e_a = (e > 0.f) ? e : 0.2f * e;
    }
    float mx = wredMax(e_a);
    float x0 = (lane < deg) ? __expf(e_a - mx) : 0.f;
    float inv = 1.f / (wredSum(x0) + 1e-16f);

    auto FETCH = [&](int jj, uint2& u, float& al){
      int s  = __shfl(s_l, jj);
      al = __shfl(x0, jj) * inv;
      u = *((const uint2*)(h8 + (size_t)s * DIM) + lane);
    };
    uint2 u0, u1, u2, u3, u4, u5, u6, u7;
    float f0, f1, f2, f3, f4, f5, f6, f7;
    if (deg > 0) FETCH(0, u0, f0);
    if (deg > 1) FETCH(1, u1, f1);
    if (deg > 2) FETCH(2, u2, f2);
    if (deg > 3) FETCH(3, u3, f3);
    if (deg > 4) FETCH(4, u4, f4);
    if (deg > 5) FETCH(5, u5, f5);
    if (deg > 6) FETCH(6, u6, f6);
    if (deg > 7) FETCH(7, u7, f7);
    for (int j = 0; j < deg; j += 8){
      consumeF8(ac, u0, f0); if (j + 8  < deg) FETCH(j + 8,  u0, f0);
      if (j + 1 >= deg) break;
      consumeF8(ac, u1, f1); if (j + 9  < deg) FETCH(j + 9,  u1, f1);
      if (j + 2 >= deg) break;
      consumeF8(ac, u2, f2); if (j + 10 < deg) FETCH(j + 10, u2, f2);
      if (j + 3 >= deg) break;
      consumeF8(ac, u3, f3); if (j + 11 < deg) FETCH(j + 11, u3, f3);
      if (j + 4 >= deg) break;
      consumeF8(ac, u4, f4); if (j + 12 < deg) FETCH(j + 12, u4, f4);
      if (j + 5 >= deg) break;
      consumeF8(ac, u5, f5); if (j + 13 < deg) FETCH(j + 13, u5, f5);
      if (j + 6 >= deg) break;
      consumeF8(ac, u6, f6); if (j + 14 < deg) FETCH(j + 14, u6, f6);
      if (j + 7 >= deg) break;
      consumeF8(ac, u7, f7); if (j + 15 < deg) FETCH(j + 15, u7, f7);
    }
  } else {
    // 64 < deg <= 128 (rare): two lane-batches, unpipelined consume
    int s_l0 = 0, s_l1 = 0;
    float e_a = -__builtin_inff(), e_b = -__builtin_inff();
    {
      int2 c = row[lane]; s_l0 = c.x;                 // lane < 64 <= deg
      float e = __int_as_float(c.y) + adi; e_a = (e > 0.f) ? e : 0.2f * e;
    }
    if (64 + lane < deg){
      int2 c = row[64 + lane]; s_l1 = c.x;
      float e = __int_as_float(c.y) + adi; e_b = (e > 0.f) ? e : 0.2f * e;
    }
    float mx = wredMax(fmaxf(e_a, e_b));
    float x0 = __expf(e_a - mx);
    float x1 = (64 + lane < deg) ? __expf(e_b - mx) : 0.f;
    float inv = 1.f / (wredSum(x0 + x1) + 1e-16f);
    for (int j = 0; j < deg; ++j){
      int s  = __shfl((j < 64) ? s_l0 : s_l1, j & 63);
      float al = __shfl((j < 64) ? x0 : x1, j & 63) * inv;
      uint2 u = *((const uint2*)(h8 + (size_t)s * DIM) + lane);
      consumeF8(ac, u, al);
    }
  }

  float4 bc0 = ((const float4*)bconv)[lane * 2];
  float4 bc1 = ((const float4*)bconv)[lane * 2 + 1];
  ac[0] += bc0.x; ac[1] += bc0.y; ac[2] += bc0.z; ac[3] += bc0.w;
  ac[4] += bc1.x; ac[5] += bc1.y; ac[6] += bc1.z; ac[7] += bc1.w;
  unsigned w0 = pk4f8(ac[0], ac[1], ac[2], ac[3]);
  unsigned w1 = pk4f8(ac[4], ac[5], ac[6], ac[7]);
  ((uint2*)(hconv8 + (size_t)i * DIM))[lane] = make_uint2(w0, w1);
  float4 wg0 = ((const float4*)Wg)[lane * 2];
  float4 wg1 = ((const float4*)Wg)[lane * 2 + 1];
  float gp = ac[0]*wg0.x + ac[1]*wg0.y + ac[2]*wg0.z + ac[3]*wg0.w
           + ac[4]*wg1.x + ac[5]*wg1.y + ac[6]*wg1.z + ac[7]*wg1.w;
  gp = wredSum(gp);
  if (lane == 0) gate[i] = gp + bg[0];
}

// per-graph sum of exp(gate), LDS-aggregated (~784 global atomics total)
__global__ void k_gsum(const float* __restrict__ gate, const int* __restrict__ batch, float* gsum){
  __shared__ float sm[GQ];
  int t = threadIdx.x, i = blockIdx.x * 512 + t;
  if (t < GQ) sm[t] = 0.f;
  __syncthreads();
  if (i < N_NODES) atomicAdd(&sm[batch[i]], __expf(gate[i]));
  __syncthreads();
  if (t < GQ && sm[t] != 0.f) atomicAdd(&gsum[t], sm[t]);
}

// fused: g = exp(gate)/gsum (written to out_g) + pp[g][c] = sum g_i*hconv[i][c]
__global__ __launch_bounds__(256) void k_pool(const unsigned char* __restrict__ hconv8,
                                              const int* __restrict__ batch,
                                              const float* __restrict__ gate,
                                              const float* __restrict__ gsum,
                                              float* __restrict__ out_g, float* pp){
  __shared__ float gv_s[128];
  __shared__ int b_s[128];
  int t = threadIdx.x;
  int base = blockIdx.x * 128;
  if (t < 128){
    int i = base + t;
    if (i < N_NODES){
      int b = batch[i];
      float gv = __expf(gate[i]) / (gsum[b] + 1e-16f);
      gv_s[t] = gv; b_s[t] = b;
      out_g[i] = gv;
    } else { gv_s[t] = 0.f; b_s[t] = -1; }
  }
  __syncthreads();
  int lim = N_NODES - base; if (lim > 128) lim = 128;
  float ax = 0.f, ay = 0.f;
  int cur = b_s[0];
#pragma unroll 4
  for (int r = 0; r < lim; ++r){
    int b = b_s[r];
    float gv = gv_s[r];
    if (b != cur){
      atomicAdd(&pp[cur * DIM + 2 * t], ax);
      atomicAdd(&pp[cur * DIM + 2 * t + 1], ay);
      ax = ay = 0.f; cur = b;
    }
    unsigned us = *(const unsigned short*)(hconv8 + (size_t)(base + r) * DIM + 2 * t);
    auto p = __builtin_amdgcn_cvt_pk_f32_fp8(us, false);
    ax += gv * p[0];
    ay += gv * p[1];
  }
  if (cur >= 0){
    atomicAdd(&pp[cur * DIM + 2 * t], ax);
    atomicAdd(&pp[cur * DIM + 2 * t + 1], ay);
  }
}

// dst[g][j] = (relu?)(src[g][:] . WT[j][:] + bias[j]) — 128 blocks, wave per column
template<bool RELU>
__global__ void k_headA(const float* __restrict__ src, const float* __restrict__ WT,
                        const float* __restrict__ bias, float* dst){
  __shared__ float sp[GQ * DIM];
  int t = threadIdx.x;
  for (int idx = t; idx < GQ * DIM; idx += 256) sp[idx] = src[idx];
  __syncthreads();
  int wid = t >> 6, lane = t & 63;
  int j = blockIdx.x * 4 + wid;
  const float4* wr = (const float4*)(WT + (size_t)j * DIM);
  float4 w0 = wr[lane * 2], w1 = wr[lane * 2 + 1];
  float bj = bias[j];
#pragma unroll
  for (int g = 0; g < GQ; ++g){
    const float* pg = sp + g * DIM + lane * 8;
    float s = w0.x*pg[0] + w0.y*pg[1] + w0.z*pg[2] + w0.w*pg[3]
            + w1.x*pg[4] + w1.y*pg[5] + w1.z*pg[6] + w1.w*pg[7];
    s = wredSum(s);
    if (lane == 0){
      s += bj;
      if (RELU) s = fmaxf(s, 0.f);
      dst[g * DIM + j] = s;
    }
  }
}

// out[g] = sigmoid(z1[g] . W2 + b2) — 1 block, 8 waves
__global__ void k_headC(const float* __restrict__ z1, const float* __restrict__ W2,
                        const float* __restrict__ b2, float* __restrict__ out){
  int wv = threadIdx.x >> 6, lane = threadIdx.x & 63;
  const float4* zr = (const float4*)(z1 + (size_t)wv * DIM);
  const float4* w4 = (const float4*)W2;
  float s = dot4(zr[lane * 2], w4[lane * 2]) + dot4(zr[lane * 2 + 1], w4[lane * 2 + 1]);
  s = wredSum(s);
  if (lane == 0) out[wv] = 1.f / (1.f + __expf(-(s + b2[0])));
}

// ---------------- launch ----------------
extern "C" void kernel_launch(void* const* d_in, const int* in_sizes, int n_in,
                              void* d_out, int out_size, void* d_ws, size_t ws_size,
                              hipStream_t stream){
  (void)in_sizes; (void)n_in; (void)out_size; (void)ws_size;
  const float* x   = (const float*)d_in[0];
  const int*   ei  = (const int*)d_in[1];
  const int*   bat = (const int*)d_in[2];
  const float* W   = (const float*)d_in[3];
  const float* atS = (const float*)d_in[4];
  const float* atD = (const float*)d_in[5];
  const float* bcv = (const float*)d_in[6];
  const float* Wg  = (const float*)d_in[7];
  const float* bg  = (const float*)d_in[8];
  const float* Wn  = (const float*)d_in[9];
  const float* bn  = (const float*)d_in[10];
  const float* W1  = (const float*)d_in[11];
  const float* b1  = (const float*)d_in[12];
  const float* W2  = (const float*)d_in[13];
  const float* b2  = (const float*)d_in[14];
  float* out = (float*)d_out;
  char* ws = (char*)d_ws;

  unsigned short* x_bf   = (unsigned short*)(ws + OFF_XBF);
  unsigned char*  h8     = (unsigned char*)(ws + OFF_HF8);
  unsigned char*  hconv8 = (unsigned char*)(ws + OFF_HCV8);
  int2*           cap    = (int2*)(ws + OFF_CAP);
  unsigned short* Wt_bf  = (unsigned short*)(ws + OFF_WTBF);
  float* WnT  = (float*)(ws + OFF_WNT);
  float* W1T  = (float*)(ws + OFF_W1T);
  float* ws_s = (float*)(ws + OFF_WSS);
  float* ws_d = (float*)(ws + OFF_WSD);
  float* a_s  = (float*)(ws + OFF_AS);
  float* a_d  = (float*)(ws + OFF_AD);
  float* gate = (float*)(ws + OFF_GATE);
  int* cnt  = (int*)(ws + OFF_CNT);
  float* gsum = (float*)(ws + OFF_GSUM);
  float* pp   = (float*)(ws + OFF_PP);
  float* pool = (float*)(ws + OFF_POOL);
  float* z1   = (float*)(ws + OFF_Z1);

  hipLaunchKernelGGL(k_setup, dim3(NBLK_SCAN + 192), dim3(256), 0, stream,
                     W, atS, atD, Wn, W1, ws_s, ws_d, Wt_bf, WnT, W1T, cnt, gsum, pp);
  hipLaunchKernelGGL(k_cast, dim3(N_PAD / 4), dim3(256), 0, stream,
                     x, ws_s, ws_d, x_bf, a_s, a_d, cap);
  hipLaunchKernelGGL(k_fill, dim3((EE + 255) / 256), dim3(256), 0, stream, ei, a_s, cnt, cap);
  hipLaunchKernelGGL(k_gemm, dim3(N_PAD / 128, 2), dim3(256), 0, stream, x_bf, Wt_bf, h8);
  hipLaunchKernelGGL(k_edge, dim3(N_NODES / 4), dim3(256), 0, stream,
                     cnt, cap, a_d, h8, bcv, Wg, bg, hconv8, gate);
  hipLaunchKernelGGL(k_gsum, dim3(98), dim3(512), 0, stream, gate, bat, gsum);
  hipLaunchKernelGGL(k_pool, dim3((N_NODES + 127) / 128), dim3(256), 0, stream,
                     hconv8, bat, gate, gsum, out + GQ, pp);
  hipLaunchKernelGGL((k_headA<false>), dim3(128), dim3(256), 0, stream, pp, WnT, bn, pool);
  hipLaunchKernelGGL((k_headA<true>),  dim3(128), dim3(256), 0, stream, pool, W1T, b1, z1);
  hipLaunchKernelGGL(k_headC, dim3(1), dim3(512), 0, stream, z1, W2, b2, out);
}